// Round 7
// baseline (827.216 us; speedup 1.0000x reference)
//
#include <hip/hip_runtime.h>
#include <hip/hip_bf16.h>

#define D 64
#define BKT 128          // nodes per bucket
#define NSUB 4           // sub-bins per bucket (blockIdx&3 -> XCD-pair affinity)
#define SUBCAP 640       // records per sub-bin (worst case ~600, deterministic seed)

// round-to-nearest-even f32 -> bf16 bits
__device__ __forceinline__ unsigned short f2bf(float f) {
    unsigned u = __float_as_uint(f);
    u = (u + 0x7FFF + ((u >> 16) & 1)) >> 16;
    return (unsigned short)u;
}
__device__ __forceinline__ float bf2f(unsigned short h) {
    return __uint_as_float((unsigned)h << 16);
}

// ---------------------------------------------------------------------------
// K1: fused degree-count + bucket binning.  4 edges/thread.
// Record: {x = (n1&127)<<24 | n2, y = f32bits(exp(-d^2))}  (8 B)
// Sub-bin by blockIdx&3: temporally-clustered, die-local claims -> L2 merges.
__global__ __launch_bounds__(256) void bin_kernel(const int* __restrict__ ei,
                                                  const float* __restrict__ dist,
                                                  int* __restrict__ cnt,
                                                  int* __restrict__ bcur,
                                                  uint2* __restrict__ staging, int E) {
    int e0 = (blockIdx.x * 256 + threadIdx.x) * 4;
    int sub = blockIdx.x & (NSUB - 1);
    const int* n2p = ei + E;
    if (e0 + 3 < E) {
        int4   a = *(const int4*)(ei + e0);
        int4   c = *(const int4*)(n2p + e0);
        float4 d = *(const float4*)(dist + e0);
        int n1s[4] = {a.x, a.y, a.z, a.w};
        int n2s[4] = {c.x, c.y, c.z, c.w};
        float ds[4] = {d.x, d.y, d.z, d.w};
        #pragma unroll
        for (int k = 0; k < 4; ++k) {
            int n1 = n1s[k];
            atomicAdd(&cnt[n1], 1);
            int idx  = (n1 >> 7) * NSUB + sub;
            int slot = atomicAdd(&bcur[idx], 1);
            if (slot < SUBCAP)
                staging[(size_t)idx * SUBCAP + slot] =
                    make_uint2(((unsigned)(n1 & (BKT - 1)) << 24) | (unsigned)n2s[k],
                               __float_as_uint(__expf(-ds[k] * ds[k])));
        }
    } else {
        for (int e = e0; e < E; ++e) {
            int n1 = ei[e];
            float dv = dist[e];
            atomicAdd(&cnt[n1], 1);
            int idx  = (n1 >> 7) * NSUB + sub;
            int slot = atomicAdd(&bcur[idx], 1);
            if (slot < SUBCAP)
                staging[(size_t)idx * SUBCAP + slot] =
                    make_uint2(((unsigned)(n1 & (BKT - 1)) << 24) | (unsigned)n2p[e],
                               __float_as_uint(__expf(-dv * dv)));
        }
    }
}

// K2: rd = rsqrt(deg)   (deg >= 1 guaranteed: every node is a source)
__global__ __launch_bounds__(256) void rd_kernel(const int* __restrict__ cnt,
                                                 float* __restrict__ rd, int N) {
    int i = blockIdx.x * 256 + threadIdx.x;
    if (i < N) rd[i] = rsqrtf((float)cnt[i]);
}

// ---------------------------------------------------------------------------
// K3: h2 = bf16( rd[row] * (X @ W^T + b) ).  Register-blocked f32 GEMM.
// (rd[n1] output factor dropped: cancels under leaky_relu + L2-normalize.)
__global__ __launch_bounds__(256) void linear_kernel(const float* __restrict__ x,
                                                     const float* __restrict__ W,
                                                     const float* __restrict__ b,
                                                     const float* __restrict__ rd,
                                                     unsigned short* __restrict__ h2,
                                                     int N) {
    __shared__ float Ws[D][D + 4];   // Ws[k][d] = W[d*64+k]
    __shared__ float Xs[D][D + 4];   // Xs[k][r] = X[row0+r][k]
    __shared__ float bs[D];
    __shared__ float rds[D];
    int t = threadIdx.x;

    #pragma unroll
    for (int p = 0; p < 4; ++p) {
        int i = t * 4 + p * 1024;
        float4 v = *(const float4*)(W + i);
        int d = i >> 6, k = i & 63;
        Ws[k + 0][d] = v.x;
        Ws[k + 1][d] = v.y;
        Ws[k + 2][d] = v.z;
        Ws[k + 3][d] = v.w;
    }
    int row0 = blockIdx.x * D;
    if (t < D) {
        bs[t] = b[t];
        int row = row0 + t;
        rds[t] = (row < N) ? rd[row] : 0.0f;
    }
    #pragma unroll
    for (int p = 0; p < 4; ++p) {
        int r = (t >> 4) + p * 16;
        int c = (t & 15) * 4;
        int row = row0 + r;
        float4 v = (row < N) ? *(const float4*)(x + (size_t)row * D + c)
                             : make_float4(0.f, 0.f, 0.f, 0.f);
        Xs[c + 0][r] = v.x;
        Xs[c + 1][r] = v.y;
        Xs[c + 2][r] = v.z;
        Xs[c + 3][r] = v.w;
    }
    __syncthreads();

    int tr = (t >> 4) * 4;
    int tc = (t & 15) * 4;
    float acc[4][4];
    #pragma unroll
    for (int i = 0; i < 4; ++i)
        #pragma unroll
        for (int j = 0; j < 4; ++j) acc[i][j] = bs[tc + j];

    #pragma unroll 8
    for (int k = 0; k < D; ++k) {
        float4 xv = *(const float4*)(&Xs[k][tr]);
        float4 wv = *(const float4*)(&Ws[k][tc]);
        acc[0][0] += xv.x * wv.x; acc[0][1] += xv.x * wv.y; acc[0][2] += xv.x * wv.z; acc[0][3] += xv.x * wv.w;
        acc[1][0] += xv.y * wv.x; acc[1][1] += xv.y * wv.y; acc[1][2] += xv.y * wv.z; acc[1][3] += xv.y * wv.w;
        acc[2][0] += xv.z * wv.x; acc[2][1] += xv.z * wv.y; acc[2][2] += xv.z * wv.z; acc[2][3] += xv.z * wv.w;
        acc[3][0] += xv.w * wv.x; acc[3][1] += xv.w * wv.y; acc[3][2] += xv.w * wv.z; acc[3][3] += xv.w * wv.w;
    }

    #pragma unroll
    for (int i = 0; i < 4; ++i) {
        int row = row0 + tr + i;
        if (row < N) {
            float sc = rds[tr + i];
            ushort4 o;
            o.x = f2bf(acc[i][0] * sc);
            o.y = f2bf(acc[i][1] * sc);
            o.z = f2bf(acc[i][2] * sc);
            o.w = f2bf(acc[i][3] * sc);
            *(ushort4*)(h2 + (size_t)row * D + tc) = o;
        }
    }
}

// ---------------------------------------------------------------------------
// K4: per-bucket aggregation in LDS + fused leaky_relu + L2-normalize.
// One block (256 thr = 4 waves) per bucket of 128 nodes; acc[128][64] f32 = 32 KB.
// Waves stream records 4-deep (4 gathers in flight); LDS float atomicAdd
// (lanes consecutive -> 2-way banking, free).
__global__ __launch_bounds__(256) void agg2_kernel(const uint2* __restrict__ staging,
                                                   const int* __restrict__ bcur,
                                                   const unsigned short* __restrict__ h2,
                                                   float* __restrict__ out, int N) {
    __shared__ float acc[BKT * D];   // 32 KB
    int b = blockIdx.x;
    int t = threadIdx.x;
    for (int i = t; i < BKT * D; i += 256) acc[i] = 0.f;
    __syncthreads();

    int lane = t & 63, wv = t >> 6;  // 4 waves
    for (int s = 0; s < NSUB; ++s) {
        int idx = b * NSUB + s;
        int nr = bcur[idx];
        if (nr > SUBCAP) nr = SUBCAP;
        const uint2* rp = staging + (size_t)idx * SUBCAP;
        int i = wv;
        for (; i + 12 < nr; i += 16) {           // 4 records/wave/iter
            uint2 r0 = rp[i];
            uint2 r1 = rp[i + 4];
            uint2 r2 = rp[i + 8];
            uint2 r3 = rp[i + 12];
            float v0 = bf2f(h2[(size_t)(r0.x & 0xFFFFFF) * D + lane]);
            float v1 = bf2f(h2[(size_t)(r1.x & 0xFFFFFF) * D + lane]);
            float v2 = bf2f(h2[(size_t)(r2.x & 0xFFFFFF) * D + lane]);
            float v3 = bf2f(h2[(size_t)(r3.x & 0xFFFFFF) * D + lane]);
            atomicAdd(&acc[(r0.x >> 24) * D + lane], __uint_as_float(r0.y) * v0);
            atomicAdd(&acc[(r1.x >> 24) * D + lane], __uint_as_float(r1.y) * v1);
            atomicAdd(&acc[(r2.x >> 24) * D + lane], __uint_as_float(r2.y) * v2);
            atomicAdd(&acc[(r3.x >> 24) * D + lane], __uint_as_float(r3.y) * v3);
        }
        for (; i < nr; i += 4) {
            uint2 r = rp[i];
            float v = bf2f(h2[(size_t)(r.x & 0xFFFFFF) * D + lane]);
            atomicAdd(&acc[(r.x >> 24) * D + lane], __uint_as_float(r.y) * v);
        }
    }
    __syncthreads();

    // finalize: leaky_relu + L2-normalize, coalesced write
    for (int loc = wv; loc < BKT; loc += 4) {
        int node = b * BKT + loc;
        if (node >= N) break;
        float x = acc[loc * D + lane];
        float v = x > 0.0f ? x : 0.01f * x;
        float ss = v * v;
        #pragma unroll
        for (int m = 32; m; m >>= 1) ss += __shfl_xor(ss, m, 64);
        out[(size_t)node * D + lane] = v / fmaxf(sqrtf(ss), 1e-12f);
    }
}

extern "C" void kernel_launch(void* const* d_in, const int* in_sizes, int n_in,
                              void* d_out, int out_size, void* d_ws, size_t ws_size,
                              hipStream_t stream) {
    const float* poi  = (const float*)d_in[0];
    const int*   ei   = (const int*)d_in[1];
    const float* dist = (const float*)d_in[2];
    const float* W    = (const float*)d_in[3];
    const float* b    = (const float*)d_in[4];
    float*       out  = (float*)d_out;

    int N = in_sizes[0] / D;   // 100000
    int E = in_sizes[2];       // 1280000

    int nbkt = (N + BKT - 1) / BKT;   // 782

    // Workspace map (extents audited; N=100000):
    //   cnt     0x000000 .. 0x061A80   (N ints)
    //   rd      0x080000 .. 0x0E1A80   (N floats)
    //   bcur    0x100000 .. 0x103100   (782*4 ints = 12.5 KB)
    //   h2      0x200000 .. 0xE35000   (N*D*2 = 12.8 MB, bf16)
    //   staging 0xE40000 .. +782*4*640*8 = 16.0 MB -> ends ~0x1D86000 (30.9 MB)
    char*           w       = (char*)d_ws;
    int*            cnt     = (int*)(w);
    float*          rd      = (float*)(w + 0x80000);
    int*            bcur    = (int*)(w + 0x100000);
    unsigned short* h2      = (unsigned short*)(w + 0x200000);
    uint2*          staging = (uint2*)(w + 0xE40000);

    hipMemsetAsync(cnt, 0, (size_t)N * sizeof(int), stream);
    hipMemsetAsync(bcur, 0, (size_t)nbkt * NSUB * sizeof(int), stream);

    bin_kernel   <<<(E / 4 + 255) / 256, 256, 0, stream>>>(ei, dist, cnt, bcur, staging, E);
    rd_kernel    <<<(N + 255) / 256, 256, 0, stream>>>(cnt, rd, N);
    linear_kernel<<<(N + D - 1) / D, 256, 0, stream>>>(poi, W, b, rd, h2, N);
    agg2_kernel  <<<nbkt, 256, 0, stream>>>(staging, bcur, h2, out, N);
}

// Round 8
// 345.233 us; speedup vs baseline: 2.3961x; 2.3961x over previous
//
#include <hip/hip_runtime.h>
#include <hip/hip_bf16.h>

#define D 64
#define NX 8          // XCD sub-CSR domains (blockIdx&7 ~ round-robin XCD map)

// round-to-nearest-even f32 -> bf16 bits
__device__ __forceinline__ unsigned short f2bf(float f) {
    unsigned u = __float_as_uint(f);
    u = (u + 0x7FFF + ((u >> 16) & 1)) >> 16;
    return (unsigned short)u;
}
__device__ __forceinline__ float bf2f(unsigned short h) {
    return __uint_as_float((unsigned)h << 16);
}

// ---------------------------------------------------------------------------
// K1: per-XCD degree histogram.  4 edges/thread; domain = blockIdx&7.
__global__ __launch_bounds__(256) void deg8_kernel(const int* __restrict__ n1,
                                                   int* __restrict__ cnt8,
                                                   int N, int E) {
    int e0 = (blockIdx.x * 256 + threadIdx.x) * 4;
    int* c = cnt8 + (size_t)(blockIdx.x & (NX - 1)) * N;
    if (e0 + 3 < E) {
        int4 v = *(const int4*)(n1 + e0);
        atomicAdd(&c[v.x], 1);
        atomicAdd(&c[v.y], 1);
        atomicAdd(&c[v.z], 1);
        atomicAdd(&c[v.w], 1);
    } else {
        for (int e = e0; e < E; ++e) atomicAdd(&c[n1[e]], 1);
    }
}

// ---------------------------------------------------------------------------
// 3-phase exclusive scan over cnt8[M], M = 8N.  8192 elems/block.
__global__ __launch_bounds__(256) void scanA_kernel(const int* __restrict__ cnt,
                                                    int* __restrict__ bsum, int M) {
    int t = threadIdx.x;
    int base = blockIdx.x * 8192 + t * 32;
    int s = 0;
    #pragma unroll
    for (int v = 0; v < 8; ++v) {
        int idx = base + v * 4;
        if (idx < M) {                       // M%4==0 -> full int4 ok
            int4 q = *(const int4*)(cnt + idx);
            s += q.x + q.y + q.z + q.w;
        }
    }
    #pragma unroll
    for (int m = 32; m; m >>= 1) s += __shfl_xor(s, m, 64);
    __shared__ int ws[4];
    if ((t & 63) == 0) ws[t >> 6] = s;
    __syncthreads();
    if (t == 0) bsum[blockIdx.x] = ws[0] + ws[1] + ws[2] + ws[3];
}

__global__ __launch_bounds__(128) void scanB_kernel(int* __restrict__ bsum, int nb) {
    __shared__ int lds[128];
    int t = threadIdx.x;
    int v = (t < nb) ? bsum[t] : 0;
    lds[t] = v;
    __syncthreads();
    #pragma unroll
    for (int off = 1; off < 128; off <<= 1) {
        int u = (t >= off) ? lds[t - off] : 0;
        __syncthreads();
        lds[t] += u;
        __syncthreads();
    }
    if (t < nb) bsum[t] = lds[t] - v;   // exclusive
}

// scanC: emit row_ptr8 and cursor8.  cursor8 ALIASES cnt (read-into-regs
// first, then overwrite — per-block ranges are disjoint, so this is safe).
__global__ __launch_bounds__(256) void scanC_kernel(int* cntcur /*in: cnt, out: cursor*/,
                                                    const int* __restrict__ bsum,
                                                    int* __restrict__ rp8,
                                                    int M, int E) {
    int t = threadIdx.x;
    int base = blockIdx.x * 8192 + t * 32;
    int c[32];
    int s = 0;
    #pragma unroll
    for (int v = 0; v < 8; ++v) {
        int idx = base + v * 4;
        int4 q = (idx < M) ? *(const int4*)(cntcur + idx) : make_int4(0, 0, 0, 0);
        c[v * 4 + 0] = q.x; c[v * 4 + 1] = q.y; c[v * 4 + 2] = q.z; c[v * 4 + 3] = q.w;
        s += q.x + q.y + q.z + q.w;
    }
    __shared__ int lds[256];
    lds[t] = s;
    __syncthreads();
    #pragma unroll
    for (int off = 1; off < 256; off <<= 1) {
        int u = (t >= off) ? lds[t - off] : 0;
        __syncthreads();
        lds[t] += u;
        __syncthreads();
    }
    int run = bsum[blockIdx.x] + lds[t] - s;
    #pragma unroll
    for (int k = 0; k < 32; ++k) {
        int i = base + k;
        if (i < M) {
            rp8[i]    = run;
            cntcur[i] = run;   // cursor init
            run += c[k];
        }
    }
    if (blockIdx.x == 0 && t == 0) rp8[M] = E;
}

// K2: rd[i] = rsqrt(total degree) from row_ptr8 diffs (deg >= 1 guaranteed)
__global__ __launch_bounds__(256) void rd_kernel(const int* __restrict__ rp8,
                                                 float* __restrict__ rd, int N) {
    int i = blockIdx.x * 256 + threadIdx.x;
    if (i >= N) return;
    int d = 0;
    #pragma unroll
    for (int x = 0; x < NX; ++x)
        d += rp8[(size_t)x * N + i + 1] - rp8[(size_t)x * N + i];
    rd[i] = rsqrtf((float)d);
}

// ---------------------------------------------------------------------------
// K3: h2 = bf16( rd[row] * (X @ W^T + b) ).  Register-blocked f32 GEMM.
// (rd[n1] output factor dropped: cancels under leaky_relu + L2-normalize.)
__global__ __launch_bounds__(256) void linear_kernel(const float* __restrict__ x,
                                                     const float* __restrict__ W,
                                                     const float* __restrict__ b,
                                                     const float* __restrict__ rd,
                                                     unsigned short* __restrict__ h2,
                                                     int N) {
    __shared__ float Ws[D][D + 4];
    __shared__ float Xs[D][D + 4];
    __shared__ float bs[D];
    __shared__ float rds[D];
    int t = threadIdx.x;

    #pragma unroll
    for (int p = 0; p < 4; ++p) {
        int i = t * 4 + p * 1024;
        float4 v = *(const float4*)(W + i);
        int d = i >> 6, k = i & 63;
        Ws[k + 0][d] = v.x;
        Ws[k + 1][d] = v.y;
        Ws[k + 2][d] = v.z;
        Ws[k + 3][d] = v.w;
    }
    int row0 = blockIdx.x * D;
    if (t < D) {
        bs[t] = b[t];
        int row = row0 + t;
        rds[t] = (row < N) ? rd[row] : 0.0f;
    }
    #pragma unroll
    for (int p = 0; p < 4; ++p) {
        int r = (t >> 4) + p * 16;
        int ccol = (t & 15) * 4;
        int row = row0 + r;
        float4 v = (row < N) ? *(const float4*)(x + (size_t)row * D + ccol)
                             : make_float4(0.f, 0.f, 0.f, 0.f);
        Xs[ccol + 0][r] = v.x;
        Xs[ccol + 1][r] = v.y;
        Xs[ccol + 2][r] = v.z;
        Xs[ccol + 3][r] = v.w;
    }
    __syncthreads();

    int tr = (t >> 4) * 4;
    int tc = (t & 15) * 4;
    float acc[4][4];
    #pragma unroll
    for (int i = 0; i < 4; ++i)
        #pragma unroll
        for (int j = 0; j < 4; ++j) acc[i][j] = bs[tc + j];

    #pragma unroll 8
    for (int k = 0; k < D; ++k) {
        float4 xv = *(const float4*)(&Xs[k][tr]);
        float4 wv = *(const float4*)(&Ws[k][tc]);
        acc[0][0] += xv.x * wv.x; acc[0][1] += xv.x * wv.y; acc[0][2] += xv.x * wv.z; acc[0][3] += xv.x * wv.w;
        acc[1][0] += xv.y * wv.x; acc[1][1] += xv.y * wv.y; acc[1][2] += xv.y * wv.z; acc[1][3] += xv.y * wv.w;
        acc[2][0] += xv.z * wv.x; acc[2][1] += xv.z * wv.y; acc[2][2] += xv.z * wv.z; acc[2][3] += xv.z * wv.w;
        acc[3][0] += xv.w * wv.x; acc[3][1] += xv.w * wv.y; acc[3][2] += xv.w * wv.z; acc[3][3] += xv.w * wv.w;
    }

    #pragma unroll
    for (int i = 0; i < 4; ++i) {
        int row = row0 + tr + i;
        if (row < N) {
            float sc = rds[tr + i];
            ushort4 o;
            o.x = f2bf(acc[i][0] * sc);
            o.y = f2bf(acc[i][1] * sc);
            o.z = f2bf(acc[i][2] * sc);
            o.w = f2bf(acc[i][3] * sc);
            *(ushort4*)(h2 + (size_t)row * D + tc) = o;
        }
    }
}

// ---------------------------------------------------------------------------
// K4: CSR fill into per-XCD sub-regions.  Domain = blockIdx&7 — identical
// edge->block mapping as deg8, so capacities match exactly.  All slot claims
// for (xcd, node) come from one XCD -> its L2 merges lines -> WRITE ~ footprint.
__global__ __launch_bounds__(256) void fill8_kernel(const int* __restrict__ ei,
                                                    const float* __restrict__ dist,
                                                    int* __restrict__ cur8,
                                                    uint2* __restrict__ csr,
                                                    int N, int E) {
    int e0 = (blockIdx.x * 256 + threadIdx.x) * 4;
    int* cur = cur8 + (size_t)(blockIdx.x & (NX - 1)) * N;
    const int* n2p = ei + E;
    if (e0 + 3 < E) {
        int4   a = *(const int4*)(ei + e0);
        int4   c = *(const int4*)(n2p + e0);
        float4 d = *(const float4*)(dist + e0);
        int s0 = atomicAdd(&cur[a.x], 1);
        int s1 = atomicAdd(&cur[a.y], 1);
        int s2 = atomicAdd(&cur[a.z], 1);
        int s3 = atomicAdd(&cur[a.w], 1);
        csr[s0] = make_uint2((unsigned)c.x, __float_as_uint(__expf(-d.x * d.x)));
        csr[s1] = make_uint2((unsigned)c.y, __float_as_uint(__expf(-d.y * d.y)));
        csr[s2] = make_uint2((unsigned)c.z, __float_as_uint(__expf(-d.z * d.z)));
        csr[s3] = make_uint2((unsigned)c.w, __float_as_uint(__expf(-d.w * d.w)));
    } else {
        for (int e = e0; e < E; ++e) {
            float dv = dist[e];
            int slot = atomicAdd(&cur[ei[e]], 1);
            csr[slot] = make_uint2((unsigned)n2p[e], __float_as_uint(__expf(-dv * dv)));
        }
    }
}

// K5: gather-side aggregation + leaky_relu + L2-normalize.
// One wave per node; walks the node's 8 per-XCD segments; register accumulate.
__global__ __launch_bounds__(256) void agg_kernel(const int* __restrict__ rp8,
                                                  const uint2* __restrict__ csr,
                                                  const unsigned short* __restrict__ h2,
                                                  float* __restrict__ out, int N) {
    int node = blockIdx.x * 4 + (threadIdx.x >> 6);
    int lane = threadIdx.x & 63;
    if (node >= N) return;
    float a0 = 0.f, a1 = 0.f;
    #pragma unroll
    for (int x = 0; x < NX; ++x) {
        const int* rp = rp8 + (size_t)x * N + node;
        int s = rp[0];
        int e = rp[1];
        int j = s;
        for (; j + 1 < e; j += 2) {
            uint2 r0 = csr[j];
            uint2 r1 = csr[j + 1];
            a0 += __uint_as_float(r0.y) * bf2f(h2[(size_t)r0.x * D + lane]);
            a1 += __uint_as_float(r1.y) * bf2f(h2[(size_t)r1.x * D + lane]);
        }
        if (j < e) {
            uint2 r = csr[j];
            a0 += __uint_as_float(r.y) * bf2f(h2[(size_t)r.x * D + lane]);
        }
    }
    float acc = a0 + a1;
    float v = acc > 0.0f ? acc : 0.01f * acc;
    float ss = v * v;
    #pragma unroll
    for (int m = 32; m; m >>= 1) ss += __shfl_xor(ss, m, 64);
    out[(size_t)node * D + lane] = v / fmaxf(sqrtf(ss), 1e-12f);
}

extern "C" void kernel_launch(void* const* d_in, const int* in_sizes, int n_in,
                              void* d_out, int out_size, void* d_ws, size_t ws_size,
                              hipStream_t stream) {
    const float* poi  = (const float*)d_in[0];
    const int*   ei   = (const int*)d_in[1];
    const float* dist = (const float*)d_in[2];
    const float* W    = (const float*)d_in[3];
    const float* b    = (const float*)d_in[4];
    float*       out  = (float*)d_out;

    int N = in_sizes[0] / D;   // 100000
    int E = in_sizes[2];       // 1280000
    int M = NX * N;            // 800000 flat scan length

    // Workspace map (extents audited; N=100000):
    //   cnt8/cursor8 0x000000 .. 0x30D400   (8N ints, 3.2MB; cursor aliases cnt)
    //   rp8          0x310000 .. 0x61D404   (8N+1 ints)
    //   rd           0x620000 .. 0x681A80   (N floats)
    //   bsum         0x690000 .. 0x690188   (98 ints)
    //   h2           0x700000 .. 0x1335000  (N*D*2 = 12.8MB bf16)
    //   csr          0x1340000 .. 0x1D04000 (E*8 = 10.24MB)  total ~30.4MB
    char*           w    = (char*)d_ws;
    int*            cnt8 = (int*)(w);            // also cursor8 after scanC
    int*            rp8  = (int*)(w + 0x310000);
    float*          rd   = (float*)(w + 0x620000);
    int*            bsum = (int*)(w + 0x690000);
    unsigned short* h2   = (unsigned short*)(w + 0x700000);
    uint2*          csr  = (uint2*)(w + 0x1340000);

    int nb = (M + 8191) / 8192;   // 98 (must be <= 128)

    hipMemsetAsync(cnt8, 0, (size_t)M * sizeof(int), stream);

    deg8_kernel  <<<(E / 4 + 255) / 256, 256, 0, stream>>>(ei, cnt8, N, E);
    scanA_kernel <<<nb, 256, 0, stream>>>(cnt8, bsum, M);
    scanB_kernel <<<1, 128, 0, stream>>>(bsum, nb);
    scanC_kernel <<<nb, 256, 0, stream>>>(cnt8, bsum, rp8, M, E);
    rd_kernel    <<<(N + 255) / 256, 256, 0, stream>>>(rp8, rd, N);
    linear_kernel<<<(N + D - 1) / D, 256, 0, stream>>>(poi, W, b, rd, h2, N);
    fill8_kernel <<<(E / 4 + 255) / 256, 256, 0, stream>>>(ei, dist, cnt8, csr, N, E);
    agg_kernel   <<<(N + 3) / 4, 256, 0, stream>>>(rp8, csr, h2, out, N);
}

// Round 9
// 258.134 us; speedup vs baseline: 3.2046x; 1.3374x over previous
//
#include <hip/hip_runtime.h>
#include <hip/hip_bf16.h>

#define D 64
#define CAP 48        // slots per node; max degree ~= 1 + Pois(11.8), P(>=48) ~ 1e-14

// round-to-nearest-even f32 -> bf16 bits
__device__ __forceinline__ unsigned short f2bf(float f) {
    unsigned u = __float_as_uint(f);
    u = (u + 0x7FFF + ((u >> 16) & 1)) >> 16;
    return (unsigned short)u;
}
__device__ __forceinline__ float bf2f(unsigned short h) {
    return __uint_as_float((unsigned)h << 16);
}

// ---------------------------------------------------------------------------
// K1: fused degree-count + direct-slot CSR fill.  4 edges/thread.
// Record (4 B): wd_q(15b) << 17 | n2(17b),  wd_q = round(exp(-d^2) * 32767).
// One atomic per edge does BOTH the degree histogram and the slot claim.
__global__ __launch_bounds__(256) void fillcap_kernel(const int* __restrict__ ei,
                                                      const float* __restrict__ dist,
                                                      int* __restrict__ cnt,
                                                      unsigned* __restrict__ csr, int E) {
    int e0 = (blockIdx.x * 256 + threadIdx.x) * 4;
    const int* n2p = ei + E;
    if (e0 + 3 < E) {
        int4   a = *(const int4*)(ei + e0);
        int4   c = *(const int4*)(n2p + e0);
        float4 d = *(const float4*)(dist + e0);
        // pack records first (keeps post-atomic dependency = address+store only)
        unsigned r0 = ((unsigned)__float2int_rn(__expf(-d.x * d.x) * 32767.f) << 17) | (unsigned)c.x;
        unsigned r1 = ((unsigned)__float2int_rn(__expf(-d.y * d.y) * 32767.f) << 17) | (unsigned)c.y;
        unsigned r2 = ((unsigned)__float2int_rn(__expf(-d.z * d.z) * 32767.f) << 17) | (unsigned)c.z;
        unsigned r3 = ((unsigned)__float2int_rn(__expf(-d.w * d.w) * 32767.f) << 17) | (unsigned)c.w;
        int s0 = atomicAdd(&cnt[a.x], 1);
        int s1 = atomicAdd(&cnt[a.y], 1);
        int s2 = atomicAdd(&cnt[a.z], 1);
        int s3 = atomicAdd(&cnt[a.w], 1);
        if (s0 < CAP) csr[(size_t)a.x * CAP + s0] = r0;
        if (s1 < CAP) csr[(size_t)a.y * CAP + s1] = r1;
        if (s2 < CAP) csr[(size_t)a.z * CAP + s2] = r2;
        if (s3 < CAP) csr[(size_t)a.w * CAP + s3] = r3;
    } else {
        for (int e = e0; e < E; ++e) {
            float dv = dist[e];
            unsigned rec = ((unsigned)__float2int_rn(__expf(-dv * dv) * 32767.f) << 17)
                           | (unsigned)n2p[e];
            int n1 = ei[e];
            int slot = atomicAdd(&cnt[n1], 1);
            if (slot < CAP) csr[(size_t)n1 * CAP + slot] = rec;
        }
    }
}

// ---------------------------------------------------------------------------
// K2: h2 = bf16( rsqrt(deg[row]) * (X @ W^T + b) ).  Register-blocked f32 GEMM,
// 64 rows/block, 4x4 tile/thread.  rd computed here from cnt (post-fill);
// the rd[n1] output factor is dropped (cancels under leaky_relu + normalize).
__global__ __launch_bounds__(256) void linear_kernel(const float* __restrict__ x,
                                                     const float* __restrict__ W,
                                                     const float* __restrict__ b,
                                                     const int* __restrict__ cnt,
                                                     unsigned short* __restrict__ h2,
                                                     int N) {
    __shared__ float Ws[D][D + 4];   // Ws[k][d] = W[d*64+k]
    __shared__ float Xs[D][D + 4];   // Xs[k][r] = X[row0+r][k]
    __shared__ float bs[D];
    __shared__ float rds[D];
    int t = threadIdx.x;

    #pragma unroll
    for (int p = 0; p < 4; ++p) {
        int i = t * 4 + p * 1024;
        float4 v = *(const float4*)(W + i);
        int d = i >> 6, k = i & 63;
        Ws[k + 0][d] = v.x;
        Ws[k + 1][d] = v.y;
        Ws[k + 2][d] = v.z;
        Ws[k + 3][d] = v.w;
    }
    int row0 = blockIdx.x * D;
    if (t < D) {
        bs[t] = b[t];
        int row = row0 + t;
        rds[t] = (row < N) ? rsqrtf((float)cnt[row]) : 0.0f;  // deg >= 1 guaranteed
    }
    #pragma unroll
    for (int p = 0; p < 4; ++p) {
        int r = (t >> 4) + p * 16;
        int ccol = (t & 15) * 4;
        int row = row0 + r;
        float4 v = (row < N) ? *(const float4*)(x + (size_t)row * D + ccol)
                             : make_float4(0.f, 0.f, 0.f, 0.f);
        Xs[ccol + 0][r] = v.x;
        Xs[ccol + 1][r] = v.y;
        Xs[ccol + 2][r] = v.z;
        Xs[ccol + 3][r] = v.w;
    }
    __syncthreads();

    int tr = (t >> 4) * 4;
    int tc = (t & 15) * 4;
    float acc[4][4];
    #pragma unroll
    for (int i = 0; i < 4; ++i)
        #pragma unroll
        for (int j = 0; j < 4; ++j) acc[i][j] = bs[tc + j];

    #pragma unroll 8
    for (int k = 0; k < D; ++k) {
        float4 xv = *(const float4*)(&Xs[k][tr]);
        float4 wv = *(const float4*)(&Ws[k][tc]);
        acc[0][0] += xv.x * wv.x; acc[0][1] += xv.x * wv.y; acc[0][2] += xv.x * wv.z; acc[0][3] += xv.x * wv.w;
        acc[1][0] += xv.y * wv.x; acc[1][1] += xv.y * wv.y; acc[1][2] += xv.y * wv.z; acc[1][3] += xv.y * wv.w;
        acc[2][0] += xv.z * wv.x; acc[2][1] += xv.z * wv.y; acc[2][2] += xv.z * wv.z; acc[2][3] += xv.z * wv.w;
        acc[3][0] += xv.w * wv.x; acc[3][1] += xv.w * wv.y; acc[3][2] += xv.w * wv.z; acc[3][3] += xv.w * wv.w;
    }

    #pragma unroll
    for (int i = 0; i < 4; ++i) {
        int row = row0 + tr + i;
        if (row < N) {
            float sc = rds[tr + i];
            ushort4 o;
            o.x = f2bf(acc[i][0] * sc);
            o.y = f2bf(acc[i][1] * sc);
            o.z = f2bf(acc[i][2] * sc);
            o.w = f2bf(acc[i][3] * sc);
            *(ushort4*)(h2 + (size_t)row * D + tc) = o;
        }
    }
}

// ---------------------------------------------------------------------------
// K3: gather-side aggregation + leaky_relu + L2-normalize.
// One wave per node; contiguous slot segment [node*CAP, node*CAP+len);
// 4-deep unroll keeps 4 row-gathers in flight.
__global__ __launch_bounds__(256) void aggcap_kernel(const int* __restrict__ cnt,
                                                     const unsigned* __restrict__ csr,
                                                     const unsigned short* __restrict__ h2,
                                                     float* __restrict__ out, int N) {
    int node = blockIdx.x * 4 + (threadIdx.x >> 6);
    int lane = threadIdx.x & 63;
    if (node >= N) return;
    int len = cnt[node];
    if (len > CAP) len = CAP;
    const unsigned* rp = csr + (size_t)node * CAP;
    const float kInv = 1.0f / 32767.0f;
    float a0 = 0.f, a1 = 0.f, a2 = 0.f, a3 = 0.f;
    int j = 0;
    for (; j + 3 < len; j += 4) {
        unsigned r0 = rp[j + 0];
        unsigned r1 = rp[j + 1];
        unsigned r2 = rp[j + 2];
        unsigned r3 = rp[j + 3];
        float v0 = bf2f(h2[(size_t)(r0 & 0x1FFFF) * D + lane]);
        float v1 = bf2f(h2[(size_t)(r1 & 0x1FFFF) * D + lane]);
        float v2 = bf2f(h2[(size_t)(r2 & 0x1FFFF) * D + lane]);
        float v3 = bf2f(h2[(size_t)(r3 & 0x1FFFF) * D + lane]);
        a0 += (float)(r0 >> 17) * kInv * v0;
        a1 += (float)(r1 >> 17) * kInv * v1;
        a2 += (float)(r2 >> 17) * kInv * v2;
        a3 += (float)(r3 >> 17) * kInv * v3;
    }
    for (; j < len; ++j) {
        unsigned r = rp[j];
        a0 += (float)(r >> 17) * kInv * bf2f(h2[(size_t)(r & 0x1FFFF) * D + lane]);
    }
    float acc = (a0 + a1) + (a2 + a3);
    float v = acc > 0.0f ? acc : 0.01f * acc;
    float ss = v * v;
    #pragma unroll
    for (int m = 32; m; m >>= 1) ss += __shfl_xor(ss, m, 64);
    out[(size_t)node * D + lane] = v / fmaxf(sqrtf(ss), 1e-12f);
}

extern "C" void kernel_launch(void* const* d_in, const int* in_sizes, int n_in,
                              void* d_out, int out_size, void* d_ws, size_t ws_size,
                              hipStream_t stream) {
    const float* poi  = (const float*)d_in[0];
    const int*   ei   = (const int*)d_in[1];
    const float* dist = (const float*)d_in[2];
    const float* W    = (const float*)d_in[3];
    const float* b    = (const float*)d_in[4];
    float*       out  = (float*)d_out;

    int N = in_sizes[0] / D;   // 100000
    int E = in_sizes[2];       // 1280000

    // Workspace map (extents audited; N=100000 -> N*4 = 0x61A80):
    //   cnt  0x000000 .. 0x061A80   (N ints)
    //   h2   0x070000 .. 0xCA5000   (N*D*2 = 12.8 MB bf16)
    //   csr  0xCB0000 .. 0xCB0000 + N*CAP*4 = +19.2 MB -> ends ~0x1EFF800 (32.5 MB)
    char*           w   = (char*)d_ws;
    int*            cnt = (int*)(w);
    unsigned short* h2  = (unsigned short*)(w + 0x70000);
    unsigned*       csr = (unsigned*)(w + 0xCB0000);

    hipMemsetAsync(cnt, 0, (size_t)N * sizeof(int), stream);

    fillcap_kernel<<<(E + 1023) / 1024, 256, 0, stream>>>(ei, dist, cnt, csr, E);
    linear_kernel <<<(N + D - 1) / D, 256, 0, stream>>>(poi, W, b, cnt, h2, N);
    aggcap_kernel <<<(N + 3) / 4, 256, 0, stream>>>(cnt, csr, h2, out, N);
}

// Round 10
// 239.233 us; speedup vs baseline: 3.4578x; 1.0790x over previous
//
#include <hip/hip_runtime.h>
#include <hip/hip_bf16.h>

#define D 64
#define CAP 48        // slots per node; max degree ~= 1 + Pois(11.8), P(>=48) ~ 1e-14

// round-to-nearest-even f32 -> bf16 bits
__device__ __forceinline__ unsigned short f2bf(float f) {
    unsigned u = __float_as_uint(f);
    u = (u + 0x7FFF + ((u >> 16) & 1)) >> 16;
    return (unsigned short)u;
}
__device__ __forceinline__ float bf2f(unsigned short h) {
    return __uint_as_float((unsigned)h << 16);
}

// ---------------------------------------------------------------------------
// K1: fused degree-count + direct-slot CSR fill.  4 edges/thread.
// Record (4 B): wd_q(15b) << 17 | n2(17b),  wd_q = round(exp(-d^2) * 32767).
// One atomic per edge does BOTH the degree histogram and the slot claim.
__global__ __launch_bounds__(256) void fillcap_kernel(const int* __restrict__ ei,
                                                      const float* __restrict__ dist,
                                                      int* __restrict__ cnt,
                                                      unsigned* __restrict__ csr, int E) {
    int e0 = (blockIdx.x * 256 + threadIdx.x) * 4;
    const int* n2p = ei + E;
    if (e0 + 3 < E) {
        int4   a = *(const int4*)(ei + e0);
        int4   c = *(const int4*)(n2p + e0);
        float4 d = *(const float4*)(dist + e0);
        unsigned r0 = ((unsigned)__float2int_rn(__expf(-d.x * d.x) * 32767.f) << 17) | (unsigned)c.x;
        unsigned r1 = ((unsigned)__float2int_rn(__expf(-d.y * d.y) * 32767.f) << 17) | (unsigned)c.y;
        unsigned r2 = ((unsigned)__float2int_rn(__expf(-d.z * d.z) * 32767.f) << 17) | (unsigned)c.z;
        unsigned r3 = ((unsigned)__float2int_rn(__expf(-d.w * d.w) * 32767.f) << 17) | (unsigned)c.w;
        int s0 = atomicAdd(&cnt[a.x], 1);
        int s1 = atomicAdd(&cnt[a.y], 1);
        int s2 = atomicAdd(&cnt[a.z], 1);
        int s3 = atomicAdd(&cnt[a.w], 1);
        if (s0 < CAP) csr[(size_t)a.x * CAP + s0] = r0;
        if (s1 < CAP) csr[(size_t)a.y * CAP + s1] = r1;
        if (s2 < CAP) csr[(size_t)a.z * CAP + s2] = r2;
        if (s3 < CAP) csr[(size_t)a.w * CAP + s3] = r3;
    } else {
        for (int e = e0; e < E; ++e) {
            float dv = dist[e];
            unsigned rec = ((unsigned)__float2int_rn(__expf(-dv * dv) * 32767.f) << 17)
                           | (unsigned)n2p[e];
            int n1 = ei[e];
            int slot = atomicAdd(&cnt[n1], 1);
            if (slot < CAP) csr[(size_t)n1 * CAP + slot] = rec;
        }
    }
}

// ---------------------------------------------------------------------------
// K2: h2 = bf16( rsqrt(deg[row]) * (X @ W^T + b) ).  Register-blocked f32 GEMM.
// rd computed from final cnt; rd[n1] output factor dropped (cancels under
// leaky_relu + L2-normalize).
__global__ __launch_bounds__(256) void linear_kernel(const float* __restrict__ x,
                                                     const float* __restrict__ W,
                                                     const float* __restrict__ b,
                                                     const int* __restrict__ cnt,
                                                     unsigned short* __restrict__ h2,
                                                     int N) {
    __shared__ float Ws[D][D + 4];
    __shared__ float Xs[D][D + 4];
    __shared__ float bs[D];
    __shared__ float rds[D];
    int t = threadIdx.x;

    #pragma unroll
    for (int p = 0; p < 4; ++p) {
        int i = t * 4 + p * 1024;
        float4 v = *(const float4*)(W + i);
        int d = i >> 6, k = i & 63;
        Ws[k + 0][d] = v.x;
        Ws[k + 1][d] = v.y;
        Ws[k + 2][d] = v.z;
        Ws[k + 3][d] = v.w;
    }
    int row0 = blockIdx.x * D;
    if (t < D) {
        bs[t] = b[t];
        int row = row0 + t;
        rds[t] = (row < N) ? rsqrtf((float)cnt[row]) : 0.0f;  // deg >= 1 guaranteed
    }
    #pragma unroll
    for (int p = 0; p < 4; ++p) {
        int r = (t >> 4) + p * 16;
        int ccol = (t & 15) * 4;
        int row = row0 + r;
        float4 v = (row < N) ? *(const float4*)(x + (size_t)row * D + ccol)
                             : make_float4(0.f, 0.f, 0.f, 0.f);
        Xs[ccol + 0][r] = v.x;
        Xs[ccol + 1][r] = v.y;
        Xs[ccol + 2][r] = v.z;
        Xs[ccol + 3][r] = v.w;
    }
    __syncthreads();

    int tr = (t >> 4) * 4;
    int tc = (t & 15) * 4;
    float acc[4][4];
    #pragma unroll
    for (int i = 0; i < 4; ++i)
        #pragma unroll
        for (int j = 0; j < 4; ++j) acc[i][j] = bs[tc + j];

    #pragma unroll 8
    for (int k = 0; k < D; ++k) {
        float4 xv = *(const float4*)(&Xs[k][tr]);
        float4 wv = *(const float4*)(&Ws[k][tc]);
        acc[0][0] += xv.x * wv.x; acc[0][1] += xv.x * wv.y; acc[0][2] += xv.x * wv.z; acc[0][3] += xv.x * wv.w;
        acc[1][0] += xv.y * wv.x; acc[1][1] += xv.y * wv.y; acc[1][2] += xv.y * wv.z; acc[1][3] += xv.y * wv.w;
        acc[2][0] += xv.z * wv.x; acc[2][1] += xv.z * wv.y; acc[2][2] += xv.z * wv.z; acc[2][3] += xv.z * wv.w;
        acc[3][0] += xv.w * wv.x; acc[3][1] += xv.w * wv.y; acc[3][2] += xv.w * wv.z; acc[3][3] += xv.w * wv.w;
    }

    #pragma unroll
    for (int i = 0; i < 4; ++i) {
        int row = row0 + tr + i;
        if (row < N) {
            float sc = rds[tr + i];
            ushort4 o;
            o.x = f2bf(acc[i][0] * sc);
            o.y = f2bf(acc[i][1] * sc);
            o.z = f2bf(acc[i][2] * sc);
            o.w = f2bf(acc[i][3] * sc);
            *(ushort4*)(h2 + (size_t)row * D + tc) = o;
        }
    }
}

// ---------------------------------------------------------------------------
// K3: gather-side aggregation + leaky_relu + L2-normalize.
// One wave per node, split into 4x16-lane groups: group g handles record j+g,
// each lane loads ushort4 (8B) = 4 dims.  One VMEM gathers 4 rows (4x the MLP
// of the old 1-record-per-wave layout); unroll-2 -> 8 records in flight.
// Epilogue: shfl_xor(16,32) folds groups; shfl_xor(1..8) gives the norm.
__global__ __launch_bounds__(256) void aggcap_kernel(const int* __restrict__ cnt,
                                                     const unsigned* __restrict__ csr,
                                                     const unsigned short* __restrict__ h2,
                                                     float* __restrict__ out, int N) {
    int node = blockIdx.x * 4 + (threadIdx.x >> 6);
    int lane = threadIdx.x & 63;
    if (node >= N) return;
    int len = cnt[node];
    if (len > CAP) len = CAP;
    const unsigned* rp = csr + (size_t)node * CAP;
    int g  = lane >> 4;          // record group 0..3
    int c4 = (lane & 15) * 4;    // this lane's 4 dims
    const float kInv = 1.0f / 32767.0f;
    float ax = 0.f, ay = 0.f, az = 0.f, aw = 0.f;
    float bx = 0.f, by = 0.f, bz = 0.f, bw = 0.f;
    int j = 0;
    for (; j + 7 < len; j += 8) {
        unsigned r0 = rp[j + g];
        unsigned r1 = rp[j + 4 + g];
        ushort4 v0 = *(const ushort4*)(h2 + (size_t)(r0 & 0x1FFFF) * D + c4);
        ushort4 v1 = *(const ushort4*)(h2 + (size_t)(r1 & 0x1FFFF) * D + c4);
        float w0 = (float)(r0 >> 17) * kInv;
        float w1 = (float)(r1 >> 17) * kInv;
        ax += w0 * bf2f(v0.x); ay += w0 * bf2f(v0.y);
        az += w0 * bf2f(v0.z); aw += w0 * bf2f(v0.w);
        bx += w1 * bf2f(v1.x); by += w1 * bf2f(v1.y);
        bz += w1 * bf2f(v1.z); bw += w1 * bf2f(v1.w);
    }
    for (; j < len; j += 4) {
        int idx = j + g;
        if (idx < len) {
            unsigned r = rp[idx];
            ushort4 v = *(const ushort4*)(h2 + (size_t)(r & 0x1FFFF) * D + c4);
            float w = (float)(r >> 17) * kInv;
            ax += w * bf2f(v.x); ay += w * bf2f(v.y);
            az += w * bf2f(v.z); aw += w * bf2f(v.w);
        }
    }
    ax += bx; ay += by; az += bz; aw += bw;
    // fold the 4 record-groups (lanes differing in bits 4,5 share dims)
    #pragma unroll
    for (int m = 16; m <= 32; m <<= 1) {
        ax += __shfl_xor(ax, m, 64);
        ay += __shfl_xor(ay, m, 64);
        az += __shfl_xor(az, m, 64);
        aw += __shfl_xor(aw, m, 64);
    }
    float vx = ax > 0.f ? ax : 0.01f * ax;
    float vy = ay > 0.f ? ay : 0.01f * ay;
    float vz = az > 0.f ? az : 0.01f * az;
    float vw = aw > 0.f ? aw : 0.01f * aw;
    float ss = vx * vx + vy * vy + vz * vz + vw * vw;
    #pragma unroll
    for (int m = 1; m <= 8; m <<= 1) ss += __shfl_xor(ss, m, 64);
    if (g == 0) {
        float inv = 1.0f / fmaxf(sqrtf(ss), 1e-12f);
        *(float4*)(out + (size_t)node * D + c4) =
            make_float4(vx * inv, vy * inv, vz * inv, vw * inv);
    }
}

extern "C" void kernel_launch(void* const* d_in, const int* in_sizes, int n_in,
                              void* d_out, int out_size, void* d_ws, size_t ws_size,
                              hipStream_t stream) {
    const float* poi  = (const float*)d_in[0];
    const int*   ei   = (const int*)d_in[1];
    const float* dist = (const float*)d_in[2];
    const float* W    = (const float*)d_in[3];
    const float* b    = (const float*)d_in[4];
    float*       out  = (float*)d_out;

    int N = in_sizes[0] / D;   // 100000
    int E = in_sizes[2];       // 1280000

    // Workspace map (extents audited; N=100000 -> N*4 = 0x61A80):
    //   cnt  0x000000 .. 0x061A80   (N ints)
    //   h2   0x070000 .. 0xCA5000   (N*D*2 = 12.8 MB bf16)
    //   csr  0xCB0000 .. +N*CAP*4 = 19.2 MB -> ends ~0x1EFF800 (32.5 MB)
    char*           w   = (char*)d_ws;
    int*            cnt = (int*)(w);
    unsigned short* h2  = (unsigned short*)(w + 0x70000);
    unsigned*       csr = (unsigned*)(w + 0xCB0000);

    hipMemsetAsync(cnt, 0, (size_t)N * sizeof(int), stream);

    fillcap_kernel<<<(E + 1023) / 1024, 256, 0, stream>>>(ei, dist, cnt, csr, E);
    linear_kernel <<<(N + D - 1) / D, 256, 0, stream>>>(poi, W, b, cnt, h2, N);
    aggcap_kernel <<<(N + 3) / 4, 256, 0, stream>>>(cnt, csr, h2, out, N);
}

// Round 13
// 194.542 us; speedup vs baseline: 4.2521x; 1.2297x over previous
//
#include <hip/hip_runtime.h>
#include <hip/hip_bf16.h>

#define D 64
#define CAP 48        // slots per node; max degree ~= 1 + Pois(11.8), P(>=48) ~ 1e-14

// round-to-nearest-even f32 -> bf16 bits
__device__ __forceinline__ unsigned short f2bf(float f) {
    unsigned u = __float_as_uint(f);
    u = (u + 0x7FFF + ((u >> 16) & 1)) >> 16;
    return (unsigned short)u;
}
__device__ __forceinline__ float bf2f(unsigned short h) {
    return __uint_as_float((unsigned)h << 16);
}

// ---------------------------------------------------------------------------
// K1: block-specialized fusion of {CSR fill} and {linear h2'' = XW+b}.
// Per 9 consecutive blocks: 5 linear tiles + 4 fill tiles, so both roles are
// resident on every CU from t=0 — linear's VALU work hides inside fill's
// atomic-queue stalls (fill: 11.5G scattered-atomics/s wall, VALU 0.5%).
// NOTE: linear here does NOT apply rsqrt(deg) (cnt isn't final); rdscale does.
__global__ __launch_bounds__(256) void fused_kernel(const float* __restrict__ x,
                                                    const float* __restrict__ W,
                                                    const float* __restrict__ b,
                                                    const int* __restrict__ ei,
                                                    const float* __restrict__ dist,
                                                    int* __restrict__ cnt,
                                                    unsigned* __restrict__ csr,
                                                    unsigned short* __restrict__ h2,
                                                    int N, int E,
                                                    int linTiles, int fillTiles) {
    __shared__ float Ws[D][D + 4];
    __shared__ float Xs[D][D + 4];
    __shared__ float bs[D];
    int grp = blockIdx.x / 9;
    int r   = blockIdx.x % 9;
    int t   = threadIdx.x;

    if (r >= 5) {
        // ---------------- fill role ----------------
        int tile = grp * 4 + (r - 5);
        if (tile >= fillTiles) return;
        int e0 = (tile * 256 + t) * 4;
        const int* n2p = ei + E;
        if (e0 + 3 < E) {
            int4   a = *(const int4*)(ei + e0);
            int4   c = *(const int4*)(n2p + e0);
            float4 d = *(const float4*)(dist + e0);
            unsigned r0 = ((unsigned)__float2int_rn(__expf(-d.x * d.x) * 32767.f) << 17) | (unsigned)c.x;
            unsigned r1 = ((unsigned)__float2int_rn(__expf(-d.y * d.y) * 32767.f) << 17) | (unsigned)c.y;
            unsigned r2 = ((unsigned)__float2int_rn(__expf(-d.z * d.z) * 32767.f) << 17) | (unsigned)c.z;
            unsigned r3 = ((unsigned)__float2int_rn(__expf(-d.w * d.w) * 32767.f) << 17) | (unsigned)c.w;
            int s0 = atomicAdd(&cnt[a.x], 1);
            int s1 = atomicAdd(&cnt[a.y], 1);
            int s2 = atomicAdd(&cnt[a.z], 1);
            int s3 = atomicAdd(&cnt[a.w], 1);
            if (s0 < CAP) csr[(size_t)a.x * CAP + s0] = r0;
            if (s1 < CAP) csr[(size_t)a.y * CAP + s1] = r1;
            if (s2 < CAP) csr[(size_t)a.z * CAP + s2] = r2;
            if (s3 < CAP) csr[(size_t)a.w * CAP + s3] = r3;
        } else {
            for (int e = e0; e < E; ++e) {
                float dv = dist[e];
                unsigned rec = ((unsigned)__float2int_rn(__expf(-dv * dv) * 32767.f) << 17)
                               | (unsigned)n2p[e];
                int n1 = ei[e];
                int slot = atomicAdd(&cnt[n1], 1);
                if (slot < CAP) csr[(size_t)n1 * CAP + slot] = rec;
            }
        }
        return;
    }

    // ---------------- linear role ----------------
    int tile = grp * 5 + r;
    if (tile >= linTiles) return;

    #pragma unroll
    for (int p = 0; p < 4; ++p) {
        int i = t * 4 + p * 1024;
        float4 v = *(const float4*)(W + i);
        int d = i >> 6, k = i & 63;
        Ws[k + 0][d] = v.x;
        Ws[k + 1][d] = v.y;
        Ws[k + 2][d] = v.z;
        Ws[k + 3][d] = v.w;
    }
    int row0 = tile * D;
    if (t < D) bs[t] = b[t];
    #pragma unroll
    for (int p = 0; p < 4; ++p) {
        int rr = (t >> 4) + p * 16;
        int ccol = (t & 15) * 4;
        int row = row0 + rr;
        float4 v = (row < N) ? *(const float4*)(x + (size_t)row * D + ccol)
                             : make_float4(0.f, 0.f, 0.f, 0.f);
        Xs[ccol + 0][rr] = v.x;
        Xs[ccol + 1][rr] = v.y;
        Xs[ccol + 2][rr] = v.z;
        Xs[ccol + 3][rr] = v.w;
    }
    __syncthreads();

    int tr = (t >> 4) * 4;
    int tc = (t & 15) * 4;
    float acc[4][4];
    #pragma unroll
    for (int i = 0; i < 4; ++i)
        #pragma unroll
        for (int j = 0; j < 4; ++j) acc[i][j] = bs[tc + j];

    #pragma unroll 8
    for (int k = 0; k < D; ++k) {
        float4 xv = *(const float4*)(&Xs[k][tr]);
        float4 wv = *(const float4*)(&Ws[k][tc]);
        acc[0][0] += xv.x * wv.x; acc[0][1] += xv.x * wv.y; acc[0][2] += xv.x * wv.z; acc[0][3] += xv.x * wv.w;
        acc[1][0] += xv.y * wv.x; acc[1][1] += xv.y * wv.y; acc[1][2] += xv.y * wv.z; acc[1][3] += xv.y * wv.w;
        acc[2][0] += xv.z * wv.x; acc[2][1] += xv.z * wv.y; acc[2][2] += xv.z * wv.z; acc[2][3] += xv.z * wv.w;
        acc[3][0] += xv.w * wv.x; acc[3][1] += xv.w * wv.y; acc[3][2] += xv.w * wv.z; acc[3][3] += xv.w * wv.w;
    }

    #pragma unroll
    for (int i = 0; i < 4; ++i) {
        int row = row0 + tr + i;
        if (row < N) {
            ushort4 o;
            o.x = f2bf(acc[i][0]);
            o.y = f2bf(acc[i][1]);
            o.z = f2bf(acc[i][2]);
            o.w = f2bf(acc[i][3]);
            *(ushort4*)(h2 + (size_t)row * D + tc) = o;
        }
    }
}

// ---------------------------------------------------------------------------
// K2: in-place h2 *= rsqrt(deg[row]).  16B (8 bf16) per thread, one row each.
__global__ __launch_bounds__(256) void rdscale_kernel(unsigned short* __restrict__ h2,
                                                      const int* __restrict__ cnt,
                                                      int N) {
    int gid = blockIdx.x * 256 + threadIdx.x;   // grid covers N*D/8 exactly-ish
    int i = gid * 8;
    if (i >= N * D) return;
    int row = i >> 6;
    float rd = rsqrtf((float)cnt[row]);         // deg >= 1 guaranteed
    ushort4* p = (ushort4*)(h2 + i);
    ushort4 a = p[0], c = p[1];
    a.x = f2bf(bf2f(a.x) * rd); a.y = f2bf(bf2f(a.y) * rd);
    a.z = f2bf(bf2f(a.z) * rd); a.w = f2bf(bf2f(a.w) * rd);
    c.x = f2bf(bf2f(c.x) * rd); c.y = f2bf(bf2f(c.y) * rd);
    c.z = f2bf(bf2f(c.z) * rd); c.w = f2bf(bf2f(c.w) * rd);
    p[0] = a; p[1] = c;
}

// ---------------------------------------------------------------------------
// K3: gather-side aggregation + leaky_relu + L2-normalize.  (unchanged R9)
__global__ __launch_bounds__(256) void aggcap_kernel(const int* __restrict__ cnt,
                                                     const unsigned* __restrict__ csr,
                                                     const unsigned short* __restrict__ h2,
                                                     float* __restrict__ out, int N) {
    int node = blockIdx.x * 4 + (threadIdx.x >> 6);
    int lane = threadIdx.x & 63;
    if (node >= N) return;
    int len = cnt[node];
    if (len > CAP) len = CAP;
    const unsigned* rp = csr + (size_t)node * CAP;
    int g  = lane >> 4;          // record group 0..3
    int c4 = (lane & 15) * 4;    // this lane's 4 dims
    const float kInv = 1.0f / 32767.0f;
    float ax = 0.f, ay = 0.f, az = 0.f, aw = 0.f;
    float bx = 0.f, by = 0.f, bz = 0.f, bw = 0.f;
    int j = 0;
    for (; j + 7 < len; j += 8) {
        unsigned r0 = rp[j + g];
        unsigned r1 = rp[j + 4 + g];
        ushort4 v0 = *(const ushort4*)(h2 + (size_t)(r0 & 0x1FFFF) * D + c4);
        ushort4 v1 = *(const ushort4*)(h2 + (size_t)(r1 & 0x1FFFF) * D + c4);
        float w0 = (float)(r0 >> 17) * kInv;
        float w1 = (float)(r1 >> 17) * kInv;
        ax += w0 * bf2f(v0.x); ay += w0 * bf2f(v0.y);
        az += w0 * bf2f(v0.z); aw += w0 * bf2f(v0.w);
        bx += w1 * bf2f(v1.x); by += w1 * bf2f(v1.y);
        bz += w1 * bf2f(v1.z); bw += w1 * bf2f(v1.w);
    }
    for (; j < len; j += 4) {
        int idx = j + g;
        if (idx < len) {
            unsigned r = rp[idx];
            ushort4 v = *(const ushort4*)(h2 + (size_t)(r & 0x1FFFF) * D + c4);
            float w = (float)(r >> 17) * kInv;
            ax += w * bf2f(v.x); ay += w * bf2f(v.y);
            az += w * bf2f(v.z); aw += w * bf2f(v.w);
        }
    }
    ax += bx; ay += by; az += bz; aw += bw;
    #pragma unroll
    for (int m = 16; m <= 32; m <<= 1) {
        ax += __shfl_xor(ax, m, 64);
        ay += __shfl_xor(ay, m, 64);
        az += __shfl_xor(az, m, 64);
        aw += __shfl_xor(aw, m, 64);
    }
    float vx = ax > 0.f ? ax : 0.01f * ax;
    float vy = ay > 0.f ? ay : 0.01f * ay;
    float vz = az > 0.f ? az : 0.01f * az;
    float vw = aw > 0.f ? aw : 0.01f * aw;
    float ss = vx * vx + vy * vy + vz * vz + vw * vw;
    #pragma unroll
    for (int m = 1; m <= 8; m <<= 1) ss += __shfl_xor(ss, m, 64);
    if (g == 0) {
        float inv = 1.0f / fmaxf(sqrtf(ss), 1e-12f);
        *(float4*)(out + (size_t)node * D + c4) =
            make_float4(vx * inv, vy * inv, vz * inv, vw * inv);
    }
}

extern "C" void kernel_launch(void* const* d_in, const int* in_sizes, int n_in,
                              void* d_out, int out_size, void* d_ws, size_t ws_size,
                              hipStream_t stream) {
    const float* poi  = (const float*)d_in[0];
    const int*   ei   = (const int*)d_in[1];
    const float* dist = (const float*)d_in[2];
    const float* W    = (const float*)d_in[3];
    const float* b    = (const float*)d_in[4];
    float*       out  = (float*)d_out;

    int N = in_sizes[0] / D;   // 100000
    int E = in_sizes[2];       // 1280000

    // Workspace map (extents audited; N=100000 -> N*4 = 0x61A80):
    //   cnt  0x000000 .. 0x061A80   (N ints)
    //   h2   0x070000 .. 0xCA5000   (N*D*2 = 12.8 MB bf16)
    //   csr  0xCB0000 .. +N*CAP*4 = 19.2 MB -> ends ~0x1EFF800 (32.5 MB)
    char*           w   = (char*)d_ws;
    int*            cnt = (int*)(w);
    unsigned short* h2  = (unsigned short*)(w + 0x70000);
    unsigned*       csr = (unsigned*)(w + 0xCB0000);

    int linTiles  = (N + D - 1) / D;        // 1563
    int fillTiles = (E + 1023) / 1024;      // 1250
    int grps      = max((linTiles + 4) / 5, (fillTiles + 3) / 4);  // 313

    hipMemsetAsync(cnt, 0, (size_t)N * sizeof(int), stream);

    fused_kernel  <<<grps * 9, 256, 0, stream>>>(poi, W, b, ei, dist, cnt, csr, h2,
                                                 N, E, linTiles, fillTiles);
    rdscale_kernel<<<(N * D / 8 + 255) / 256, 256, 0, stream>>>(h2, cnt, N);
    aggcap_kernel <<<(N + 3) / 4, 256, 0, stream>>>(cnt, csr, h2, out, N);
}